// Round 1
// baseline (727.275 us; speedup 1.0000x reference)
//
#include <hip/hip_runtime.h>
#include <hip/hip_bf16.h>

// Readout: logits = W2 . gelu(W1^T [nodes; z_local[batch]; z_meta] + b1) + b2
// Split GEMM: big term nodes@W1_lo via bf16 MFMA (memory-bound, ~83us roofline);
// z_local@W1_mid precomputed per-graph (pre[B,128]); z_meta@W1_hi+b1 -> bias2[128].

typedef __attribute__((ext_vector_type(8))) __bf16 bf16x8;
typedef __attribute__((ext_vector_type(4))) float f32x4;

#define D_DIM 128

// Exact-GELU via Abramowitz-Stegun 7.1.26 erf (max abs err 1.5e-7), ~12 VALU ops.
__device__ __forceinline__ float gelu_exact(float x) {
    float t = 0.70710678118654752f * x;     // x / sqrt(2)
    float a = fabsf(t);
    float d = __builtin_amdgcn_rcpf(fmaf(0.3275911f, a, 1.0f));
    float p = fmaf(1.061405429f, d, -1.453152027f);
    p = fmaf(p, d, 1.421413741f);
    p = fmaf(p, d, -0.284496736f);
    p = fmaf(p, d, 0.254829592f);
    p = p * d;
    float e = __builtin_amdgcn_exp2f(a * a * -1.4426950408889634f); // exp(-t^2)
    float erf_a = fmaf(-p, e, 1.0f);
    float erf_t = copysignf(erf_a, t);
    return 0.5f * x * (1.0f + erf_t);
}

// bias2[n] = b1[n] + sum_k z_meta[k] * W1[256+k][n]
__global__ void prep_bias2(const float* __restrict__ z_meta, const float* __restrict__ W1,
                           const float* __restrict__ b1, float* __restrict__ bias2) {
    int n = threadIdx.x;
    float s = b1[n];
    for (int k = 0; k < D_DIM; ++k)
        s = fmaf(z_meta[k], W1[(2 * D_DIM + k) * D_DIM + n], s);
    bias2[n] = s;
}

// Swizzle W1[0:128][:] (fp32) into bf16 MFMA B-fragment order:
// frag f = ((kc*8+nt)*64+lane)*8+j  holds  W1[kc*32+(lane>>4)*8+j][nt*16+(lane&15)]
__global__ void prep_w1f(const float* __restrict__ W1, __bf16* __restrict__ w1f) {
    int f = blockIdx.x * 256 + threadIdx.x;       // 16384 total
    int j = f & 7, lane = (f >> 3) & 63, nt = (f >> 9) & 7, kc = f >> 12;
    int k = kc * 32 + (lane >> 4) * 8 + j;
    int n = nt * 16 + (lane & 15);
    w1f[f] = (__bf16)W1[k * D_DIM + n];
}

// pre[b][n] = bias2[n] + sum_k z_local[b][k] * W1[128+k][n]   (fp32 exact)
__global__ __launch_bounds__(128) void prep_pre(const float* __restrict__ z_local,
                                                const float* __restrict__ W1,
                                                const float* __restrict__ bias2,
                                                float* __restrict__ pre) {
    int n = threadIdx.x;
    int g0 = blockIdx.x * 8;
    float bz = bias2[n];
    float s[8];
#pragma unroll
    for (int g = 0; g < 8; ++g) s[g] = bz;
    for (int k = 0; k < D_DIM; ++k) {
        float wk = W1[(D_DIM + k) * D_DIM + n];
#pragma unroll
        for (int g = 0; g < 8; ++g)
            s[g] = fmaf(z_local[(size_t)(g0 + g) * D_DIM + k], wk, s[g]);
    }
#pragma unroll
    for (int g = 0; g < 8; ++g) pre[(size_t)(g0 + g) * D_DIM + n] = s[g];
}

// Main: block=256 (4 waves), each wave = 16 rows x 128 cols via 8x mfma_f32_16x16x32_bf16.
// No LDS, no __syncthreads. Nodes read once (coalesced 16B/lane), W1 frags L1-hot.
__global__ __launch_bounds__(256) void readout_main(
    const float* __restrict__ nodes, const int* __restrict__ batch,
    const float* __restrict__ pre, const __bf16* __restrict__ w1f,
    const float* __restrict__ W2, const float* __restrict__ b2,
    float* __restrict__ out) {
    const int tid = threadIdx.x;
    const int wave = tid >> 6;
    const int lane = tid & 63;
    const int q = lane >> 4;     // quad index
    const int c0 = lane & 15;
    const int row_base = blockIdx.x * 64 + wave * 16;

    // Issue all HBM loads for this wave's A tile up front (16 rows x 128 k, fp32).
    const float* aptr = nodes + (size_t)(row_base + c0) * D_DIM + q * 8;
    f32x4 a[8];
#pragma unroll
    for (int kc = 0; kc < 4; ++kc) {
        a[2 * kc]     = *((const f32x4*)(aptr + kc * 32));
        a[2 * kc + 1] = *((const f32x4*)(aptr + kc * 32 + 4));
    }
    int brow[4];
#pragma unroll
    for (int r = 0; r < 4; ++r) brow[r] = batch[row_base + q * 4 + r];
    float w2v[8];
#pragma unroll
    for (int nt = 0; nt < 8; ++nt) w2v[nt] = W2[nt * 16 + c0];
    const float b2v = b2[0];

    f32x4 acc[8] = {};  // zero-init

    const bf16x8* bfr = (const bf16x8*)w1f;
#pragma unroll
    for (int kc = 0; kc < 4; ++kc) {
        bf16x8 af;
#pragma unroll
        for (int j = 0; j < 8; ++j)
            af[j] = (__bf16)a[2 * kc + (j >> 2)][j & 3];   // RNE fp32->bf16
#pragma unroll
        for (int nt = 0; nt < 8; ++nt) {
            bf16x8 bf = bfr[(kc * 8 + nt) * 64 + lane];
            acc[nt] = __builtin_amdgcn_mfma_f32_16x16x32_bf16(af, bf, acc[nt], 0, 0, 0);
        }
    }

    // Epilogue: u = acc + pre[batch[row]][col]; h = gelu(u); logit = h . W2 + b2
    // C/D layout: col = c0 (+16*nt), row = q*4 + r
#pragma unroll
    for (int r = 0; r < 4; ++r) {
        const float* prow = pre + (size_t)brow[r] * D_DIM;
        float partial = 0.f;
#pragma unroll
        for (int nt = 0; nt < 8; ++nt) {
            float u = acc[nt][r] + prow[nt * 16 + c0];
            partial += gelu_exact(u) * w2v[nt];
        }
        partial += __shfl_xor(partial, 1);
        partial += __shfl_xor(partial, 2);
        partial += __shfl_xor(partial, 4);
        partial += __shfl_xor(partial, 8);
        if (c0 == 0) out[row_base + q * 4 + r] = partial + b2v;
    }
}

extern "C" void kernel_launch(void* const* d_in, const int* in_sizes, int n_in,
                              void* d_out, int out_size, void* d_ws, size_t ws_size,
                              hipStream_t stream) {
    const float* nodes   = (const float*)d_in[0];
    const float* z_local = (const float*)d_in[1];
    const float* z_meta  = (const float*)d_in[2];
    const float* W1      = (const float*)d_in[3];
    const float* b1      = (const float*)d_in[4];
    const float* W2      = (const float*)d_in[5];
    const float* b2      = (const float*)d_in[6];
    const int*   batch   = (const int*)d_in[7];
    float* out = (float*)d_out;

    char* ws = (char*)d_ws;
    __bf16* w1f  = (__bf16*)ws;              // 16384 bf16 = 32 KB
    float* bias2 = (float*)(ws + 32768);     // 128 f32
    float* pre   = (float*)(ws + 33280);     // 4096*128 f32 = 2 MB

    prep_bias2<<<1, 128, 0, stream>>>(z_meta, W1, b1, bias2);
    prep_w1f<<<64, 256, 0, stream>>>(W1, w1f);
    prep_pre<<<512, 128, 0, stream>>>(z_local, W1, bias2, pre);

    // C = 1e6 rows, 64 rows/block -> 15625 blocks exactly
    readout_main<<<15625, 256, 0, stream>>>(nodes, batch, pre, w1f, W2, b2, out);
}

// Round 2
// 690.742 us; speedup vs baseline: 1.0529x; 1.0529x over previous
//
#include <hip/hip_runtime.h>
#include <hip/hip_bf16.h>
#include <cstdint>

// Readout: logits = W2 . gelu(W1^T [nodes; z_local[batch]; z_meta] + b1) + b2
// Split GEMM: nodes@W1_lo via bf16 MFMA (memory-bound, ~85us roofline);
// z_local@W1_mid -> pre[B,128] (fp32 exact); z_meta@W1_hi + b1 -> bias2[128].
// w1f fragments staged in LDS once per block (global_load_lds w=16).

typedef __attribute__((ext_vector_type(8))) __bf16 bf16x8;
typedef __attribute__((ext_vector_type(4))) float f32x4;
typedef __attribute__((address_space(3))) uint32_t lds_u32;
typedef __attribute__((address_space(1))) const uint32_t glob_u32;

#define D_DIM 128

// Exact-GELU via Abramowitz-Stegun 7.1.26 erf (max abs err 1.5e-7).
__device__ __forceinline__ float gelu_exact(float x) {
    float t = 0.70710678118654752f * x;     // x / sqrt(2)
    float a = fabsf(t);
    float d = __builtin_amdgcn_rcpf(fmaf(0.3275911f, a, 1.0f));
    float p = fmaf(1.061405429f, d, -1.453152027f);
    p = fmaf(p, d, 1.421413741f);
    p = fmaf(p, d, -0.284496736f);
    p = fmaf(p, d, 0.254829592f);
    p = p * d;
    float e = __builtin_amdgcn_exp2f(a * a * -1.4426950408889634f); // exp(-t^2)
    float erf_a = fmaf(-p, e, 1.0f);
    float erf_t = copysignf(erf_a, t);
    return 0.5f * x * (1.0f + erf_t);
}

// One prep kernel, 577 blocks x 256 threads, all parts independent:
//  blk 0..63  : swizzle W1[0:128][:] into bf16 MFMA B-frag order w1f
//  blk 64     : bias2[n] = b1[n] + z_meta . W1[256:384][n]
//  blk 65..576: pre[b][n] = z_local[b] . W1[128:256][n]   (NO bias2 here)
__global__ __launch_bounds__(256) void prep_all(
    const float* __restrict__ z_local, const float* __restrict__ z_meta,
    const float* __restrict__ W1, const float* __restrict__ b1,
    __bf16* __restrict__ w1f, float* __restrict__ bias2, float* __restrict__ pre) {
    const int blk = blockIdx.x;
    const int tid = threadIdx.x;
    if (blk < 64) {
        // frag f = ((kc*8+nt)*64+lane)*8+j holds W1[kc*32+(lane>>4)*8+j][nt*16+(lane&15)]
        int f = blk * 256 + tid;              // 16384 total
        int j = f & 7, lane = (f >> 3) & 63, nt = (f >> 9) & 7, kc = f >> 12;
        int k = kc * 32 + (lane >> 4) * 8 + j;
        int n = nt * 16 + (lane & 15);
        w1f[f] = (__bf16)W1[k * D_DIM + n];
    } else if (blk == 64) {
        if (tid < D_DIM) {
            int n = tid;
            float s = b1[n];
            for (int k = 0; k < D_DIM; ++k)
                s = fmaf(z_meta[k], W1[(2 * D_DIM + k) * D_DIM + n], s);
            bias2[n] = s;
        }
    } else {
        int pb = blk - 65;                    // 0..511
        int n = tid & 127;
        int g0 = pb * 8 + (tid >> 7) * 4;     // 4 graphs per half-block
        float s[4] = {0.f, 0.f, 0.f, 0.f};
        for (int k = 0; k < D_DIM; ++k) {
            float wk = W1[(D_DIM + k) * D_DIM + n];
#pragma unroll
            for (int g = 0; g < 4; ++g)
                s[g] = fmaf(z_local[(size_t)(g0 + g) * D_DIM + k], wk, s[g]);
        }
#pragma unroll
        for (int g = 0; g < 4; ++g) pre[(size_t)(g0 + g) * D_DIM + n] = s[g];
    }
}

// Main: block=256 (4 waves), each wave = 16 rows x 128 cols via 8x mfma_f32_16x16x32_bf16.
// w1f staged in LDS once per block; B-frags via ds_read_b128 (conflict-free).
__global__ __launch_bounds__(256) void readout_main(
    const float* __restrict__ nodes, const int* __restrict__ batch,
    const float* __restrict__ pre, const __bf16* __restrict__ w1f,
    const float* __restrict__ bias2, const float* __restrict__ W2,
    const float* __restrict__ b2, float* __restrict__ out) {
    __shared__ __bf16 w1s[16384];    // 32 KB
    const int tid = threadIdx.x;
    const int wave = tid >> 6;
    const int lane = tid & 63;
    const int q = lane >> 4;         // quad index
    const int c0 = lane & 15;
    const int row_base = blockIdx.x * 64 + wave * 16;

    // Issue the wave's A-tile HBM loads first (16 rows x 128 k, fp32, 16B/lane).
    const float* aptr = nodes + (size_t)(row_base + c0) * D_DIM + q * 8;
    f32x4 a[8];
#pragma unroll
    for (int kc = 0; kc < 4; ++kc) {
        a[2 * kc]     = *((const f32x4*)(aptr + kc * 32));
        a[2 * kc + 1] = *((const f32x4*)(aptr + kc * 32 + 4));
    }

    // Stage w1f -> LDS: wave w copies bytes [w*8KB, (w+1)*8KB), 16B/lane/call.
    {
        const __bf16* gsrc = w1f + wave * 4096;
        __bf16* ldst = w1s + wave * 4096;
#pragma unroll
        for (int it = 0; it < 8; ++it) {
            __builtin_amdgcn_global_load_lds(
                (glob_u32*)(gsrc + it * 512 + lane * 8),
                (lds_u32*)(ldst + it * 512), 16, 0, 0);
        }
    }

    int brow[4];
#pragma unroll
    for (int r = 0; r < 4; ++r) brow[r] = batch[row_base + q * 4 + r];
    float w2v[8], bz[8];
#pragma unroll
    for (int nt = 0; nt < 8; ++nt) {
        w2v[nt] = W2[nt * 16 + c0];
        bz[nt]  = bias2[nt * 16 + c0];
    }
    const float b2v = b2[0];

    __syncthreads();   // drains global_load_lds (vmcnt) + barrier

    f32x4 acc[8] = {};
    const bf16x8* bfr = (const bf16x8*)w1s;
#pragma unroll
    for (int kc = 0; kc < 4; ++kc) {
        bf16x8 af;
#pragma unroll
        for (int j = 0; j < 8; ++j)
            af[j] = (__bf16)a[2 * kc + (j >> 2)][j & 3];   // RNE fp32->bf16
#pragma unroll
        for (int nt = 0; nt < 8; ++nt) {
            bf16x8 bf = bfr[(kc * 8 + nt) * 64 + lane];    // ds_read_b128
            acc[nt] = __builtin_amdgcn_mfma_f32_16x16x32_bf16(af, bf, acc[nt], 0, 0, 0);
        }
    }

    // Epilogue: u = acc + pre[batch[row]][col] + bias2[col]; logit = gelu(u).W2 + b2
    // C/D layout: col = c0 + 16*nt, row = q*4 + r
#pragma unroll
    for (int r = 0; r < 4; ++r) {
        const float* prow = pre + (size_t)brow[r] * D_DIM;
        float partial = 0.f;
#pragma unroll
        for (int nt = 0; nt < 8; ++nt) {
            float u = acc[nt][r] + prow[nt * 16 + c0] + bz[nt];
            partial += gelu_exact(u) * w2v[nt];
        }
        partial += __shfl_xor(partial, 1);
        partial += __shfl_xor(partial, 2);
        partial += __shfl_xor(partial, 4);
        partial += __shfl_xor(partial, 8);
        if (c0 == 0) out[row_base + q * 4 + r] = partial + b2v;
    }
}

extern "C" void kernel_launch(void* const* d_in, const int* in_sizes, int n_in,
                              void* d_out, int out_size, void* d_ws, size_t ws_size,
                              hipStream_t stream) {
    const float* nodes   = (const float*)d_in[0];
    const float* z_local = (const float*)d_in[1];
    const float* z_meta  = (const float*)d_in[2];
    const float* W1      = (const float*)d_in[3];
    const float* b1      = (const float*)d_in[4];
    const float* W2      = (const float*)d_in[5];
    const float* b2      = (const float*)d_in[6];
    const int*   batch   = (const int*)d_in[7];
    float* out = (float*)d_out;

    char* ws = (char*)d_ws;
    __bf16* w1f  = (__bf16*)ws;              // 16384 bf16 = 32 KB
    float* bias2 = (float*)(ws + 32768);     // 128 f32
    float* pre   = (float*)(ws + 33280);     // 4096*128 f32 = 2 MB

    prep_all<<<577, 256, 0, stream>>>(z_local, z_meta, W1, b1, w1f, bias2, pre);
    // C = 1e6 rows, 64 rows/block -> 15625 blocks exactly
    readout_main<<<15625, 256, 0, stream>>>(nodes, batch, pre, w1f, bias2, W2, b2, out);
}